// Round 1
// baseline (1180.907 us; speedup 1.0000x reference)
//
#include <hip/hip_runtime.h>
#include <math.h>

#define Bm 2048
#define Hm 512
#define Em 300
#define Tm 50
#define KWm 812  // H + E

__device__ __forceinline__ float sigmoidf_(float x) { return 1.f / (1.f + __expf(-x)); }

// ---------------------------------------------------------------------------
// Kernel 1: qs[b,h] = h_enc[b,:]·lq_w[h,:] + h_summ[b,:]·ls_w[h,:] + lq_b[h] + ls_b[h]
// 64x64 tile, 256 threads, 4x4 microtile, K staged in LDS (transposed).
// ---------------------------------------------------------------------------
__global__ __launch_bounds__(256) void k_qs(
        const float* __restrict__ henc, const float* __restrict__ hsum,
        const float* __restrict__ lq, const float* __restrict__ lqb,
        const float* __restrict__ ls, const float* __restrict__ lsb,
        float* __restrict__ qs) {
    __shared__ float As[16][64];
    __shared__ float Ws[16][64];
    const int tx = threadIdx.x & 15, ty = threadIdx.x >> 4;
    const int b0 = blockIdx.x * 64, n0 = blockIdx.y * 64;
    const int lr = threadIdx.x >> 2;          // 0..63 row
    const int lk = (threadIdx.x & 3) << 2;    // 0,4,8,12 k-quad
    float acc[4][4] = {};
    for (int pass = 0; pass < 2; ++pass) {
        const float* A = pass ? hsum : henc;
        const float* W = pass ? ls : lq;
        for (int k0 = 0; k0 < 512; k0 += 16) {
            __syncthreads();
            float4 a4 = *(const float4*)&A[(size_t)(b0 + lr) * 512 + k0 + lk];
            float4 w4 = *(const float4*)&W[(size_t)(n0 + lr) * 512 + k0 + lk];
            As[lk+0][lr] = a4.x; As[lk+1][lr] = a4.y; As[lk+2][lr] = a4.z; As[lk+3][lr] = a4.w;
            Ws[lk+0][lr] = w4.x; Ws[lk+1][lr] = w4.y; Ws[lk+2][lr] = w4.z; Ws[lk+3][lr] = w4.w;
            __syncthreads();
            #pragma unroll
            for (int k = 0; k < 16; ++k) {
                float4 av = *(const float4*)&As[k][ty * 4];
                float4 wv = *(const float4*)&Ws[k][tx * 4];
                float a[4] = {av.x, av.y, av.z, av.w};
                float w[4] = {wv.x, wv.y, wv.z, wv.w};
                #pragma unroll
                for (int i = 0; i < 4; ++i)
                    #pragma unroll
                    for (int j = 0; j < 4; ++j)
                        acc[i][j] = fmaf(a[i], w[j], acc[i][j]);
            }
        }
    }
    #pragma unroll
    for (int i = 0; i < 4; ++i) {
        int b = b0 + ty * 4 + i;
        #pragma unroll
        for (int j = 0; j < 4; ++j) {
            int h = n0 + tx * 4 + j;
            qs[(size_t)b * Hm + h] = acc[i][j] + lqb[h] + lsb[h];
        }
    }
}

// ---------------------------------------------------------------------------
// Kernel 2 (dominant): for fixed t, k_tile = phi_tile @ lk_w^T; fuse
// e = tanh(qs + k + lk_b), partial score = sum_a e * v_w[a]; atomicAdd into
// scores[b,t]. Grid: (a-tiles=8, b-tiles=32, t=50).
// ---------------------------------------------------------------------------
__global__ __launch_bounds__(256) void k_scores(
        const float* __restrict__ phi, const float* __restrict__ lkw,
        const float* __restrict__ lkb, const float* __restrict__ qsb,
        const float* __restrict__ vw, float* __restrict__ scores) {
    __shared__ float As[16][64];
    __shared__ float Ws[16][64];
    __shared__ float red[64][17];
    const int tx = threadIdx.x & 15, ty = threadIdx.x >> 4;
    const int a0 = blockIdx.x * 64;
    const int b0 = blockIdx.y * 64;
    const int t  = blockIdx.z;
    const float* A = phi + ((size_t)t * Bm + b0) * Hm;
    const int lr = threadIdx.x >> 2;
    const int lk = (threadIdx.x & 3) << 2;
    float acc[4][4] = {};
    for (int k0 = 0; k0 < 512; k0 += 16) {
        __syncthreads();
        float4 a4 = *(const float4*)&A[(size_t)lr * Hm + k0 + lk];
        float4 w4 = *(const float4*)&lkw[(size_t)(a0 + lr) * Hm + k0 + lk];
        As[lk+0][lr] = a4.x; As[lk+1][lr] = a4.y; As[lk+2][lr] = a4.z; As[lk+3][lr] = a4.w;
        Ws[lk+0][lr] = w4.x; Ws[lk+1][lr] = w4.y; Ws[lk+2][lr] = w4.z; Ws[lk+3][lr] = w4.w;
        __syncthreads();
        #pragma unroll
        for (int k = 0; k < 16; ++k) {
            float4 av = *(const float4*)&As[k][ty * 4];
            float4 wv = *(const float4*)&Ws[k][tx * 4];
            float a[4] = {av.x, av.y, av.z, av.w};
            float w[4] = {wv.x, wv.y, wv.z, wv.w};
            #pragma unroll
            for (int i = 0; i < 4; ++i)
                #pragma unroll
                for (int j = 0; j < 4; ++j)
                    acc[i][j] = fmaf(a[i], w[j], acc[i][j]);
        }
    }
    // epilogue: tanh + dot with v_w, reduce over the 16 col-thread-groups
    float part[4] = {0.f, 0.f, 0.f, 0.f};
    #pragma unroll
    for (int i = 0; i < 4; ++i) {
        int b = b0 + ty * 4 + i;
        #pragma unroll
        for (int j = 0; j < 4; ++j) {
            int a = a0 + tx * 4 + j;
            float e = tanhf(acc[i][j] + qsb[(size_t)b * Hm + a] + lkb[a]);
            part[i] = fmaf(e, vw[a], part[i]);
        }
    }
    #pragma unroll
    for (int i = 0; i < 4; ++i) red[ty * 4 + i][tx] = part[i];
    __syncthreads();
    if (threadIdx.x < 64) {
        float s = 0.f;
        #pragma unroll
        for (int j = 0; j < 16; ++j) s += red[threadIdx.x][j];
        atomicAdd(&scores[(size_t)(b0 + threadIdx.x) * Tm + t], s);
    }
}

// ---------------------------------------------------------------------------
// Kernel 3: softmax over T=50 per row, then h_s / c_s weighted sums.
// One block per b, 256 threads (each covers 2 h).
// ---------------------------------------------------------------------------
__global__ __launch_bounds__(256) void k_attn(
        const float* __restrict__ phi, const float* __restrict__ cell,
        const float* __restrict__ scores,
        float* __restrict__ hs, float* __restrict__ cs) {
    __shared__ float p[Tm];
    const int b = blockIdx.x;
    const int tid = threadIdx.x;
    if (tid < 64) {
        float s = (tid < Tm) ? scores[(size_t)b * Tm + tid] : -INFINITY;
        float m = s;
        #pragma unroll
        for (int o = 32; o; o >>= 1) m = fmaxf(m, __shfl_xor(m, o));
        float ex = (tid < Tm) ? __expf(s - m) : 0.f;
        float sum = ex;
        #pragma unroll
        for (int o = 32; o; o >>= 1) sum += __shfl_xor(sum, o);
        if (tid < Tm) p[tid] = ex / sum;
    }
    __syncthreads();
    float ah0 = 0.f, ah1 = 0.f, ac0 = 0.f, ac1 = 0.f;
    for (int t = 0; t < Tm; ++t) {
        float w = p[t];
        const float* ph = phi  + ((size_t)t * Bm + b) * Hm;
        const float* ce = cell + ((size_t)t * Bm + b) * Hm;
        ah0 = fmaf(w, ph[tid], ah0);
        ah1 = fmaf(w, ph[tid + 256], ah1);
        ac0 = fmaf(w, ce[tid], ac0);
        ac1 = fmaf(w, ce[tid + 256], ac1);
    }
    hs[(size_t)b * Hm + tid]       = ah0;
    hs[(size_t)b * Hm + tid + 256] = ah1;
    cs[(size_t)b * Hm + tid]       = ac0;
    cs[(size_t)b * Hm + tid + 256] = ac1;
}

// ---------------------------------------------------------------------------
// Kernel 4: gates = [h_s, x] @ W_w^T + W_b for all 4 gates of the same (b,h)
// tile, fused LSTM epilogue -> h_ctrl. 64x64 tile, 4 gate accumulator sets.
// ---------------------------------------------------------------------------
__global__ __launch_bounds__(256) void k_gates(
        const float* __restrict__ hs, const float* __restrict__ x,
        const float* __restrict__ Ww, const float* __restrict__ Wb,
        const float* __restrict__ cs, float* __restrict__ out) {
    __shared__ float As[16][64];
    __shared__ float Ws[4][16][64];
    const int tx = threadIdx.x & 15, ty = threadIdx.x >> 4;
    const int b0 = blockIdx.x * 64, n0 = blockIdx.y * 64;
    const int lr = threadIdx.x >> 2;
    const int lk = (threadIdx.x & 3) << 2;
    float acc[4][4][4] = {};  // [gate][i][j]
    for (int k0 = 0; k0 < KWm; k0 += 16) {
        __syncthreads();
        #pragma unroll
        for (int u = 0; u < 4; ++u) {
            int kk = k0 + lk + u;
            float v = 0.f;
            if (kk < Hm)        v = hs[(size_t)(b0 + lr) * Hm + kk];
            else if (kk < KWm)  v = x[(size_t)(b0 + lr) * Em + (kk - Hm)];
            As[lk + u][lr] = v;
        }
        #pragma unroll
        for (int g = 0; g < 4; ++g) {
            #pragma unroll
            for (int u = 0; u < 4; ++u) {
                int kk = k0 + lk + u;
                float v = (kk < KWm) ? Ww[(size_t)(g * Hm + n0 + lr) * KWm + kk] : 0.f;
                Ws[g][lk + u][lr] = v;
            }
        }
        __syncthreads();
        #pragma unroll
        for (int k = 0; k < 16; ++k) {
            float4 a4 = *(const float4*)&As[k][ty * 4];
            float a[4] = {a4.x, a4.y, a4.z, a4.w};
            #pragma unroll
            for (int g = 0; g < 4; ++g) {
                float4 w4 = *(const float4*)&Ws[g][k][tx * 4];
                float w[4] = {w4.x, w4.y, w4.z, w4.w};
                #pragma unroll
                for (int i = 0; i < 4; ++i)
                    #pragma unroll
                    for (int j = 0; j < 4; ++j)
                        acc[g][i][j] = fmaf(a[i], w[j], acc[g][i][j]);
            }
        }
    }
    #pragma unroll
    for (int i = 0; i < 4; ++i) {
        int b = b0 + ty * 4 + i;
        #pragma unroll
        for (int j = 0; j < 4; ++j) {
            int h = n0 + tx * 4 + j;
            float f  = sigmoidf_(acc[0][i][j] + Wb[h]);
            float o  = sigmoidf_(acc[1][i][j] + Wb[Hm + h]);
            float ii = sigmoidf_(acc[2][i][j] + Wb[2 * Hm + h]);
            float ch = tanhf(acc[3][i][j] + Wb[3 * Hm + h]);
            float c  = f * cs[(size_t)b * Hm + h] + ii * ch;
            out[(size_t)b * Hm + h] = o * tanhf(c);
        }
    }
}

extern "C" void kernel_launch(void* const* d_in, const int* in_sizes, int n_in,
                              void* d_out, int out_size, void* d_ws, size_t ws_size,
                              hipStream_t stream) {
    const float* x      = (const float*)d_in[0];
    const float* h_enc  = (const float*)d_in[1];
    const float* phi    = (const float*)d_in[2];
    const float* cell   = (const float*)d_in[3];
    const float* h_summ = (const float*)d_in[4];
    // d_in[5] c_summ: unused by the reference
    const float* W_w    = (const float*)d_in[6];
    const float* W_b    = (const float*)d_in[7];
    const float* v_w    = (const float*)d_in[8];
    // d_in[9] v_b: constant across t -> softmax-invariant, dropped
    const float* lq_w   = (const float*)d_in[10];
    const float* lq_b   = (const float*)d_in[11];
    const float* lk_w   = (const float*)d_in[12];
    const float* lk_b   = (const float*)d_in[13];
    const float* ls_w   = (const float*)d_in[14];
    const float* ls_b   = (const float*)d_in[15];
    float* out = (float*)d_out;

    float* qs     = (float*)d_ws;                       // B*H
    float* scores = qs + (size_t)Bm * Hm;               // B*T
    float* hs     = scores + (size_t)Bm * Tm;           // B*H
    float* cs     = hs + (size_t)Bm * Hm;               // B*H

    hipMemsetAsync(scores, 0, (size_t)Bm * Tm * sizeof(float), stream);
    k_qs<<<dim3(Bm / 64, Hm / 64), 256, 0, stream>>>(h_enc, h_summ, lq_w, lq_b, ls_w, ls_b, qs);
    k_scores<<<dim3(Hm / 64, Bm / 64, Tm), 256, 0, stream>>>(phi, lk_w, lk_b, qs, v_w, scores);
    k_attn<<<dim3(Bm), 256, 0, stream>>>(phi, cell, scores, hs, cs);
    k_gates<<<dim3(Bm / 64, Hm / 64), 256, 0, stream>>>(hs, x, W_w, W_b, cs, out);
}

// Round 2
// 663.918 us; speedup vs baseline: 1.7787x; 1.7787x over previous
//
#include <hip/hip_runtime.h>
#include <math.h>

#define Bm 2048
#define Hm 512
#define Em 300
#define Tm 50
#define KWm 812  // H + E

typedef unsigned short u16;
typedef __attribute__((ext_vector_type(8))) short short8;
typedef __attribute__((ext_vector_type(8))) u16 ushort8v;
typedef __attribute__((ext_vector_type(4))) float f32x4;

__device__ __forceinline__ float sigmoidf_(float x) { return 1.f / (1.f + __expf(-x)); }

// fp32 -> bf16 bits, round-to-nearest-even
__device__ __forceinline__ u16 bfr(float x) {
    union { float f; unsigned int u; } c; c.f = x;
    unsigned int u = c.u;
    u += 0x7FFFu + ((u >> 16) & 1u);
    return (u16)(u >> 16);
}
__device__ __forceinline__ ushort8v cvt8(const float* __restrict__ p) {
    f32x4 v0 = *(const f32x4*)p;
    f32x4 v1 = *(const f32x4*)(p + 4);
    ushort8v r;
    r[0] = bfr(v0[0]); r[1] = bfr(v0[1]); r[2] = bfr(v0[2]); r[3] = bfr(v0[3]);
    r[4] = bfr(v1[0]); r[5] = bfr(v1[1]); r[6] = bfr(v1[2]); r[7] = bfr(v1[3]);
    return r;
}

// ---------------------------------------------------------------------------
// Kernel 1: qs2[b,h] = h_enc[b,:]·lq_w[h,:] + h_summ[b,:]·ls_w[h,:]
//                      + lq_b[h] + ls_b[h] + lk_b[h]   (lk_b folded in)
// ---------------------------------------------------------------------------
__global__ __launch_bounds__(256) void k_qs(
        const float* __restrict__ henc, const float* __restrict__ hsum,
        const float* __restrict__ lq, const float* __restrict__ lqb,
        const float* __restrict__ ls, const float* __restrict__ lsb,
        const float* __restrict__ lkb, float* __restrict__ qs) {
    __shared__ float As[16][64];
    __shared__ float Ws[16][64];
    const int tx = threadIdx.x & 15, ty = threadIdx.x >> 4;
    const int b0 = blockIdx.x * 64, n0 = blockIdx.y * 64;
    const int lr = threadIdx.x >> 2;
    const int lk = (threadIdx.x & 3) << 2;
    float acc[4][4] = {};
    for (int pass = 0; pass < 2; ++pass) {
        const float* A = pass ? hsum : henc;
        const float* W = pass ? ls : lq;
        for (int k0 = 0; k0 < 512; k0 += 16) {
            __syncthreads();
            f32x4 a4 = *(const f32x4*)&A[(size_t)(b0 + lr) * 512 + k0 + lk];
            f32x4 w4 = *(const f32x4*)&W[(size_t)(n0 + lr) * 512 + k0 + lk];
            As[lk+0][lr] = a4[0]; As[lk+1][lr] = a4[1]; As[lk+2][lr] = a4[2]; As[lk+3][lr] = a4[3];
            Ws[lk+0][lr] = w4[0]; Ws[lk+1][lr] = w4[1]; Ws[lk+2][lr] = w4[2]; Ws[lk+3][lr] = w4[3];
            __syncthreads();
            #pragma unroll
            for (int k = 0; k < 16; ++k) {
                f32x4 av = *(const f32x4*)&As[k][ty * 4];
                f32x4 wv = *(const f32x4*)&Ws[k][tx * 4];
                #pragma unroll
                for (int i = 0; i < 4; ++i)
                    #pragma unroll
                    for (int j = 0; j < 4; ++j)
                        acc[i][j] = fmaf(av[i], wv[j], acc[i][j]);
            }
        }
    }
    #pragma unroll
    for (int i = 0; i < 4; ++i) {
        int b = b0 + ty * 4 + i;
        #pragma unroll
        for (int j = 0; j < 4; ++j) {
            int h = n0 + tx * 4 + j;
            qs[(size_t)b * Hm + h] = acc[i][j] + lqb[h] + lsb[h] + lkb[h];
        }
    }
}

// ---------------------------------------------------------------------------
// Kernel 2 (dominant): one big GEMM  E = phi_flat(102400x512) @ lk_w^T(512x512)
// in bf16 MFMA (on-the-fly fp32->bf16 staging), fused epilogue
//   scores[b,t] += sum_a tanh(E + qs2[b,a]) * v_w[a]
// 128x128 tile, 4 waves 2x2, 4x4 frags of mfma_f32_16x16x32_bf16, BK=32.
// Each 128-row M-tile has a single t (2048 % 128 == 0).
// ---------------------------------------------------------------------------
__global__ __launch_bounds__(256) void k_scores_mfma(
        const float* __restrict__ phi, const float* __restrict__ lkw,
        const float* __restrict__ qs2, const float* __restrict__ vw,
        float* __restrict__ scores) {
    __shared__ u16 Asl[128 * 32];
    __shared__ u16 Bsl[128 * 32];
    const int m0 = blockIdx.y * 128;
    const int n0 = blockIdx.x * 128;
    const int t  = m0 >> 11;            // row / 2048
    const int b0 = m0 & (Bm - 1);
    const int tid  = threadIdx.x;
    const int lane = tid & 63;
    const int wid  = tid >> 6;
    const int wr = wid >> 1, wc = wid & 1;     // 2x2 wave grid
    const int row   = tid >> 1;                // staging row 0..127
    const int halfk = (tid & 1) << 4;          // 0 or 16 elems
    const int l15 = lane & 15;
    const int l4  = lane >> 4;

    f32x4 acc[4][4];
    #pragma unroll
    for (int i = 0; i < 4; ++i)
        #pragma unroll
        for (int j = 0; j < 4; ++j)
            acc[i][j] = (f32x4){0.f, 0.f, 0.f, 0.f};

    for (int k0 = 0; k0 < 512; k0 += 32) {
        __syncthreads();
        const float* ga = phi + (size_t)(m0 + row) * 512 + k0 + halfk;
        const float* gb = lkw + (size_t)(n0 + row) * 512 + k0 + halfk;
        *(ushort8v*)&Asl[row * 32 + halfk]     = cvt8(ga);
        *(ushort8v*)&Asl[row * 32 + halfk + 8] = cvt8(ga + 8);
        *(ushort8v*)&Bsl[row * 32 + halfk]     = cvt8(gb);
        *(ushort8v*)&Bsl[row * 32 + halfk + 8] = cvt8(gb + 8);
        __syncthreads();
        short8 af[4], bf[4];
        #pragma unroll
        for (int mf = 0; mf < 4; ++mf)
            af[mf] = *(const short8*)&Asl[(wr * 64 + mf * 16 + l15) * 32 + l4 * 8];
        #pragma unroll
        for (int nf = 0; nf < 4; ++nf)
            bf[nf] = *(const short8*)&Bsl[(wc * 64 + nf * 16 + l15) * 32 + l4 * 8];
        #pragma unroll
        for (int mf = 0; mf < 4; ++mf)
            #pragma unroll
            for (int nf = 0; nf < 4; ++nf)
                acc[mf][nf] = __builtin_amdgcn_mfma_f32_16x16x32_bf16(
                                  af[mf], bf[nf], acc[mf][nf], 0, 0, 0);
    }

    // epilogue: tanh + v_w dot + row-sum, then one atomicAdd per row per wave
    float vws[4];
    int av[4];
    #pragma unroll
    for (int nf = 0; nf < 4; ++nf) {
        av[nf] = n0 + wc * 64 + nf * 16 + l15;
        vws[nf] = vw[av[nf]];
    }
    #pragma unroll
    for (int mf = 0; mf < 4; ++mf) {
        #pragma unroll
        for (int reg = 0; reg < 4; ++reg) {
            int b = b0 + wr * 64 + mf * 16 + l4 * 4 + reg;
            const float* q = qs2 + (size_t)b * Hm;
            float s = 0.f;
            #pragma unroll
            for (int nf = 0; nf < 4; ++nf)
                s = fmaf(tanhf(acc[mf][nf][reg] + q[av[nf]]), vws[nf], s);
            #pragma unroll
            for (int o = 1; o < 16; o <<= 1) s += __shfl_xor(s, o);
            if (l15 == 0) atomicAdd(&scores[(size_t)b * Tm + t], s);
        }
    }
}

// ---------------------------------------------------------------------------
// Kernel 3: softmax over T=50 per row, then h_s / c_s weighted sums.
// ---------------------------------------------------------------------------
__global__ __launch_bounds__(256) void k_attn(
        const float* __restrict__ phi, const float* __restrict__ cell,
        const float* __restrict__ scores,
        float* __restrict__ hs, float* __restrict__ cs) {
    __shared__ float p[Tm];
    const int b = blockIdx.x;
    const int tid = threadIdx.x;
    if (tid < 64) {
        float s = (tid < Tm) ? scores[(size_t)b * Tm + tid] : -INFINITY;
        float m = s;
        #pragma unroll
        for (int o = 32; o; o >>= 1) m = fmaxf(m, __shfl_xor(m, o));
        float ex = (tid < Tm) ? __expf(s - m) : 0.f;
        float sum = ex;
        #pragma unroll
        for (int o = 32; o; o >>= 1) sum += __shfl_xor(sum, o);
        if (tid < Tm) p[tid] = ex / sum;
    }
    __syncthreads();
    float ah0 = 0.f, ah1 = 0.f, ac0 = 0.f, ac1 = 0.f;
    for (int t = 0; t < Tm; ++t) {
        float w = p[t];
        const float* ph = phi  + ((size_t)t * Bm + b) * Hm;
        const float* ce = cell + ((size_t)t * Bm + b) * Hm;
        ah0 = fmaf(w, ph[tid], ah0);
        ah1 = fmaf(w, ph[tid + 256], ah1);
        ac0 = fmaf(w, ce[tid], ac0);
        ac1 = fmaf(w, ce[tid + 256], ac1);
    }
    hs[(size_t)b * Hm + tid]       = ah0;
    hs[(size_t)b * Hm + tid + 256] = ah1;
    cs[(size_t)b * Hm + tid]       = ac0;
    cs[(size_t)b * Hm + tid + 256] = ac1;
}

// ---------------------------------------------------------------------------
// Kernel 4: gates = [h_s, x] @ W_w^T + W_b, fused LSTM epilogue -> h_ctrl.
// ---------------------------------------------------------------------------
__global__ __launch_bounds__(256) void k_gates(
        const float* __restrict__ hs, const float* __restrict__ x,
        const float* __restrict__ Ww, const float* __restrict__ Wb,
        const float* __restrict__ cs, float* __restrict__ out) {
    __shared__ float As[16][64];
    __shared__ float Ws[4][16][64];
    const int tx = threadIdx.x & 15, ty = threadIdx.x >> 4;
    const int b0 = blockIdx.x * 64, n0 = blockIdx.y * 64;
    const int lr = threadIdx.x >> 2;
    const int lk = (threadIdx.x & 3) << 2;
    float acc[4][4][4] = {};  // [gate][i][j]
    for (int k0 = 0; k0 < KWm; k0 += 16) {
        __syncthreads();
        #pragma unroll
        for (int u = 0; u < 4; ++u) {
            int kk = k0 + lk + u;
            float v = 0.f;
            if (kk < Hm)        v = hs[(size_t)(b0 + lr) * Hm + kk];
            else if (kk < KWm)  v = x[(size_t)(b0 + lr) * Em + (kk - Hm)];
            As[lk + u][lr] = v;
        }
        #pragma unroll
        for (int g = 0; g < 4; ++g) {
            #pragma unroll
            for (int u = 0; u < 4; ++u) {
                int kk = k0 + lk + u;
                float v = (kk < KWm) ? Ww[(size_t)(g * Hm + n0 + lr) * KWm + kk] : 0.f;
                Ws[g][lk + u][lr] = v;
            }
        }
        __syncthreads();
        #pragma unroll
        for (int k = 0; k < 16; ++k) {
            f32x4 a4 = *(const f32x4*)&As[k][ty * 4];
            #pragma unroll
            for (int g = 0; g < 4; ++g) {
                f32x4 w4 = *(const f32x4*)&Ws[g][k][tx * 4];
                #pragma unroll
                for (int i = 0; i < 4; ++i)
                    #pragma unroll
                    for (int j = 0; j < 4; ++j)
                        acc[g][i][j] = fmaf(a4[i], w4[j], acc[g][i][j]);
            }
        }
    }
    #pragma unroll
    for (int i = 0; i < 4; ++i) {
        int b = b0 + ty * 4 + i;
        #pragma unroll
        for (int j = 0; j < 4; ++j) {
            int h = n0 + tx * 4 + j;
            float f  = sigmoidf_(acc[0][i][j] + Wb[h]);
            float o  = sigmoidf_(acc[1][i][j] + Wb[Hm + h]);
            float ii = sigmoidf_(acc[2][i][j] + Wb[2 * Hm + h]);
            float ch = tanhf(acc[3][i][j] + Wb[3 * Hm + h]);
            float c  = f * cs[(size_t)b * Hm + h] + ii * ch;
            out[(size_t)b * Hm + h] = o * tanhf(c);
        }
    }
}

extern "C" void kernel_launch(void* const* d_in, const int* in_sizes, int n_in,
                              void* d_out, int out_size, void* d_ws, size_t ws_size,
                              hipStream_t stream) {
    const float* x      = (const float*)d_in[0];
    const float* h_enc  = (const float*)d_in[1];
    const float* phi    = (const float*)d_in[2];
    const float* cell   = (const float*)d_in[3];
    const float* h_summ = (const float*)d_in[4];
    // d_in[5] c_summ: unused by the reference
    const float* W_w    = (const float*)d_in[6];
    const float* W_b    = (const float*)d_in[7];
    const float* v_w    = (const float*)d_in[8];
    // d_in[9] v_b: constant across t -> softmax-invariant, dropped
    const float* lq_w   = (const float*)d_in[10];
    const float* lq_b   = (const float*)d_in[11];
    const float* lk_w   = (const float*)d_in[12];
    const float* lk_b   = (const float*)d_in[13];
    const float* ls_w   = (const float*)d_in[14];
    const float* ls_b   = (const float*)d_in[15];
    float* out = (float*)d_out;

    float* qs     = (float*)d_ws;                       // B*H
    float* scores = qs + (size_t)Bm * Hm;               // B*T
    float* hs     = scores + (size_t)Bm * Tm;           // B*H
    float* cs     = hs + (size_t)Bm * Hm;               // B*H

    hipMemsetAsync(scores, 0, (size_t)Bm * Tm * sizeof(float), stream);
    k_qs<<<dim3(Bm / 64, Hm / 64), 256, 0, stream>>>(h_enc, h_summ, lq_w, lq_b, ls_w, ls_b, lk_b, qs);
    k_scores_mfma<<<dim3(Hm / 128, (Tm * Bm) / 128), 256, 0, stream>>>(phi, lk_w, qs, v_w, scores);
    k_attn<<<dim3(Bm), 256, 0, stream>>>(phi, cell, scores, hs, cs);
    k_gates<<<dim3(Bm / 64, Hm / 64), 256, 0, stream>>>(hs, x, W_w, W_b, cs, out);
}

// Round 3
// 381.497 us; speedup vs baseline: 3.0955x; 1.7403x over previous
//
#include <hip/hip_runtime.h>
#include <math.h>

#define Bm 2048
#define Hm 512
#define Em 300
#define Tm 50
#define KWm 812   // H + E
#define KWp 832   // padded to multiple of 32

typedef unsigned short u16;
typedef __attribute__((ext_vector_type(8))) short short8;
typedef __attribute__((ext_vector_type(8))) u16 ushort8v;
typedef __attribute__((ext_vector_type(4))) float f32x4;

__device__ __forceinline__ float sigmoidf_(float x) { return 1.f / (1.f + __expf(-x)); }

// fp32 -> bf16 bits, round-to-nearest-even
__device__ __forceinline__ u16 bfr(float x) {
    union { float f; unsigned int u; } c; c.f = x;
    unsigned int u = c.u;
    u += 0x7FFFu + ((u >> 16) & 1u);
    return (u16)(u >> 16);
}
__device__ __forceinline__ ushort8v cvt8(const float* __restrict__ p) {
    f32x4 v0 = *(const f32x4*)p;
    f32x4 v1 = *(const f32x4*)(p + 4);
    ushort8v r;
    r[0] = bfr(v0[0]); r[1] = bfr(v0[1]); r[2] = bfr(v0[2]); r[3] = bfr(v0[3]);
    r[4] = bfr(v1[0]); r[5] = bfr(v1[1]); r[6] = bfr(v1[2]); r[7] = bfr(v1[3]);
    return r;
}

// async global(bf16,16B) -> LDS, linear dest (wave-uniform base + lane*16)
__device__ __forceinline__ void gload16(const u16* g, u16* l) {
    __builtin_amdgcn_global_load_lds((const __attribute__((address_space(1))) void*)g,
                                     (__attribute__((address_space(3))) void*)l, 16, 0, 0);
}

// ---------------------------------------------------------------------------
// k_pack: bf16 conversions/concats done once per launch.
// job 0: Aq[2048][1024] = bf16([h_enc | h_summ])
// job 1: Wq[512][1024]  = bf16([lq_w | ls_w])
// job 2: Wg[2048][832]  = bf16(W_w) zero-padded
// job 3: Xb[2048][512..831] = bf16(x) zero-padded  (cols 0..511 filled by k_attn)
// ---------------------------------------------------------------------------
__global__ __launch_bounds__(256) void k_pack(
        const float* __restrict__ henc, const float* __restrict__ hsum,
        const float* __restrict__ lq, const float* __restrict__ ls,
        const float* __restrict__ Ww, const float* __restrict__ x,
        u16* __restrict__ Aq, u16* __restrict__ Wq,
        u16* __restrict__ Wg, u16* __restrict__ Xb) {
    const int job = blockIdx.y;
    const int r = blockIdx.x;
    const int tid = threadIdx.x;
    if (job == 0) {
        for (int c = tid; c < 1024; c += 256) {
            float v = (c < 512) ? henc[(size_t)r * 512 + c] : hsum[(size_t)r * 512 + (c - 512)];
            Aq[(size_t)r * 1024 + c] = bfr(v);
        }
    } else if (job == 1) {
        if (r < 512)
            for (int c = tid; c < 1024; c += 256) {
                float v = (c < 512) ? lq[(size_t)r * 512 + c] : ls[(size_t)r * 512 + (c - 512)];
                Wq[(size_t)r * 1024 + c] = bfr(v);
            }
    } else if (job == 2) {
        for (int c = tid; c < KWp; c += 256)
            Wg[(size_t)r * KWp + c] = (c < KWm) ? bfr(Ww[(size_t)r * KWm + c]) : (u16)0;
    } else {
        for (int c = 512 + tid; c < KWp; c += 256)
            Xb[(size_t)r * KWp + c] = (c < KWm) ? bfr(x[(size_t)r * Em + (c - 512)]) : (u16)0;
    }
}

// ---------------------------------------------------------------------------
// k_qs_mfma: qs[b,h] = [h_enc|h_summ]·[lq|ls]^T + (lq_b+ls_b+lk_b)[h]
// 64x64 tile, 4 waves 2x2, 2x2 frags, BK=32, K=1024. global_load_lds staging.
// ---------------------------------------------------------------------------
__global__ __launch_bounds__(256) void k_qs_mfma(
        const u16* __restrict__ Aq, const u16* __restrict__ Wq,
        const float* __restrict__ lqb, const float* __restrict__ lsb,
        const float* __restrict__ lkb, float* __restrict__ qs) {
    __shared__ u16 Asl[64 * 32];
    __shared__ u16 Bsl[64 * 32];
    const int m0 = blockIdx.x * 64, n0 = blockIdx.y * 64;
    const int tid = threadIdx.x, lane = tid & 63, wid = tid >> 6;
    const int wr = wid >> 1, wc = wid & 1;
    const int l15 = lane & 15, l4 = lane >> 4;
    const int srow = (wid << 4) + (lane >> 2);          // 0..63
    const int gchunk = (lane & 3) ^ ((srow >> 1) & 3);  // source-side swizzle
    f32x4 acc[2][2];
    #pragma unroll
    for (int i = 0; i < 2; ++i)
        #pragma unroll
        for (int j = 0; j < 2; ++j) acc[i][j] = (f32x4){0.f, 0.f, 0.f, 0.f};

    for (int k0 = 0; k0 < 1024; k0 += 32) {
        __syncthreads();
        gload16(Aq + (size_t)(m0 + srow) * 1024 + k0 + gchunk * 8, &Asl[wid * 512]);
        gload16(Wq + (size_t)(n0 + srow) * 1024 + k0 + gchunk * 8, &Bsl[wid * 512]);
        __syncthreads();
        short8 af[2], bf[2];
        #pragma unroll
        for (int mf = 0; mf < 2; ++mf) {
            int r = wr * 32 + mf * 16 + l15;
            af[mf] = *(const short8*)&Asl[r * 32 + (l4 ^ ((r >> 1) & 3)) * 8];
        }
        #pragma unroll
        for (int nf = 0; nf < 2; ++nf) {
            int r = wc * 32 + nf * 16 + l15;
            bf[nf] = *(const short8*)&Bsl[r * 32 + (l4 ^ ((r >> 1) & 3)) * 8];
        }
        #pragma unroll
        for (int mf = 0; mf < 2; ++mf)
            #pragma unroll
            for (int nf = 0; nf < 2; ++nf)
                acc[mf][nf] = __builtin_amdgcn_mfma_f32_16x16x32_bf16(
                                  af[mf], bf[nf], acc[mf][nf], 0, 0, 0);
    }
    #pragma unroll
    for (int mf = 0; mf < 2; ++mf)
        #pragma unroll
        for (int nf = 0; nf < 2; ++nf)
            #pragma unroll
            for (int reg = 0; reg < 4; ++reg) {
                int b = m0 + wr * 32 + mf * 16 + l4 * 4 + reg;
                int h = n0 + wc * 32 + nf * 16 + l15;
                qs[(size_t)b * Hm + h] = acc[mf][nf][reg] + lqb[h] + lsb[h] + lkb[h];
            }
}

// ---------------------------------------------------------------------------
// k_scores_mfma (dominant): E = phi_flat(102400x512) @ lk_w^T, fused
// tanh/v_w/row-sum epilogue with atomicAdd into scores. (unchanged from R2)
// ---------------------------------------------------------------------------
__global__ __launch_bounds__(256) void k_scores_mfma(
        const float* __restrict__ phi, const float* __restrict__ lkw,
        const float* __restrict__ qs2, const float* __restrict__ vw,
        float* __restrict__ scores) {
    __shared__ u16 Asl[128 * 32];
    __shared__ u16 Bsl[128 * 32];
    const int m0 = blockIdx.y * 128;
    const int n0 = blockIdx.x * 128;
    const int t  = m0 >> 11;
    const int b0 = m0 & (Bm - 1);
    const int tid  = threadIdx.x;
    const int lane = tid & 63;
    const int wid  = tid >> 6;
    const int wr = wid >> 1, wc = wid & 1;
    const int row   = tid >> 1;
    const int halfk = (tid & 1) << 4;
    const int l15 = lane & 15;
    const int l4  = lane >> 4;

    f32x4 acc[4][4];
    #pragma unroll
    for (int i = 0; i < 4; ++i)
        #pragma unroll
        for (int j = 0; j < 4; ++j) acc[i][j] = (f32x4){0.f, 0.f, 0.f, 0.f};

    for (int k0 = 0; k0 < 512; k0 += 32) {
        __syncthreads();
        const float* ga = phi + (size_t)(m0 + row) * 512 + k0 + halfk;
        const float* gb = lkw + (size_t)(n0 + row) * 512 + k0 + halfk;
        *(ushort8v*)&Asl[row * 32 + halfk]     = cvt8(ga);
        *(ushort8v*)&Asl[row * 32 + halfk + 8] = cvt8(ga + 8);
        *(ushort8v*)&Bsl[row * 32 + halfk]     = cvt8(gb);
        *(ushort8v*)&Bsl[row * 32 + halfk + 8] = cvt8(gb + 8);
        __syncthreads();
        short8 af[4], bf[4];
        #pragma unroll
        for (int mf = 0; mf < 4; ++mf)
            af[mf] = *(const short8*)&Asl[(wr * 64 + mf * 16 + l15) * 32 + l4 * 8];
        #pragma unroll
        for (int nf = 0; nf < 4; ++nf)
            bf[nf] = *(const short8*)&Bsl[(wc * 64 + nf * 16 + l15) * 32 + l4 * 8];
        #pragma unroll
        for (int mf = 0; mf < 4; ++mf)
            #pragma unroll
            for (int nf = 0; nf < 4; ++nf)
                acc[mf][nf] = __builtin_amdgcn_mfma_f32_16x16x32_bf16(
                                  af[mf], bf[nf], acc[mf][nf], 0, 0, 0);
    }

    float vws[4];
    int av[4];
    #pragma unroll
    for (int nf = 0; nf < 4; ++nf) {
        av[nf] = n0 + wc * 64 + nf * 16 + l15;
        vws[nf] = vw[av[nf]];
    }
    #pragma unroll
    for (int mf = 0; mf < 4; ++mf) {
        #pragma unroll
        for (int reg = 0; reg < 4; ++reg) {
            int b = b0 + wr * 64 + mf * 16 + l4 * 4 + reg;
            const float* q = qs2 + (size_t)b * Hm;
            float s = 0.f;
            #pragma unroll
            for (int nf = 0; nf < 4; ++nf)
                s = fmaf(tanhf(acc[mf][nf][reg] + q[av[nf]]), vws[nf], s);
            #pragma unroll
            for (int o = 1; o < 16; o <<= 1) s += __shfl_xor(s, o);
            if (l15 == 0) atomicAdd(&scores[(size_t)b * Tm + t], s);
        }
    }
}

// ---------------------------------------------------------------------------
// k_attn: softmax over T, weighted sums; h_s emitted as bf16 into Xb cols 0..511,
// c_s kept fp32 for the LSTM epilogue.
// ---------------------------------------------------------------------------
__global__ __launch_bounds__(256) void k_attn(
        const float* __restrict__ phi, const float* __restrict__ cell,
        const float* __restrict__ scores,
        u16* __restrict__ Xb, float* __restrict__ cs) {
    __shared__ float p[Tm];
    const int b = blockIdx.x;
    const int tid = threadIdx.x;
    if (tid < 64) {
        float s = (tid < Tm) ? scores[(size_t)b * Tm + tid] : -INFINITY;
        float m = s;
        #pragma unroll
        for (int o = 32; o; o >>= 1) m = fmaxf(m, __shfl_xor(m, o));
        float ex = (tid < Tm) ? __expf(s - m) : 0.f;
        float sum = ex;
        #pragma unroll
        for (int o = 32; o; o >>= 1) sum += __shfl_xor(sum, o);
        if (tid < Tm) p[tid] = ex / sum;
    }
    __syncthreads();
    float ah0 = 0.f, ah1 = 0.f, ac0 = 0.f, ac1 = 0.f;
    for (int t = 0; t < Tm; ++t) {
        float w = p[t];
        const float* ph = phi  + ((size_t)t * Bm + b) * Hm;
        const float* ce = cell + ((size_t)t * Bm + b) * Hm;
        ah0 = fmaf(w, ph[tid], ah0);
        ah1 = fmaf(w, ph[tid + 256], ah1);
        ac0 = fmaf(w, ce[tid], ac0);
        ac1 = fmaf(w, ce[tid + 256], ac1);
    }
    Xb[(size_t)b * KWp + tid]       = bfr(ah0);
    Xb[(size_t)b * KWp + tid + 256] = bfr(ah1);
    cs[(size_t)b * Hm + tid]       = ac0;
    cs[(size_t)b * Hm + tid + 256] = ac1;
}

// ---------------------------------------------------------------------------
// k_gates_mfma: gates[2048][2048] = Xb(2048x832) @ Wg^T(2048x832), bf16 MFMA.
// 64x128 tile, 4 waves 2x2 (each 32x64), BK=32. global_load_lds staging.
// ---------------------------------------------------------------------------
__global__ __launch_bounds__(256) void k_gates_mfma(
        const u16* __restrict__ Xb, const u16* __restrict__ Wg,
        float* __restrict__ gates) {
    __shared__ u16 Asl[64 * 32];
    __shared__ u16 Bsl[128 * 32];
    const int m0 = blockIdx.x * 64, n0 = blockIdx.y * 128;
    const int tid = threadIdx.x, lane = tid & 63, wid = tid >> 6;
    const int wr = wid >> 1, wc = wid & 1;
    const int l15 = lane & 15, l4 = lane >> 4;
    const int srow = (wid << 4) + (lane >> 2);          // 0..63 (A rows)
    const int gchunkA = (lane & 3) ^ ((srow >> 1) & 3);
    f32x4 acc[2][4];
    #pragma unroll
    for (int i = 0; i < 2; ++i)
        #pragma unroll
        for (int j = 0; j < 4; ++j) acc[i][j] = (f32x4){0.f, 0.f, 0.f, 0.f};

    for (int k0 = 0; k0 < KWp; k0 += 32) {
        __syncthreads();
        gload16(Xb + (size_t)(m0 + srow) * KWp + k0 + gchunkA * 8, &Asl[wid * 512]);
        #pragma unroll
        for (int j = 0; j < 2; ++j) {
            int brow = (wid << 5) + (j << 4) + (lane >> 2);   // 0..127 (B rows)
            int gchunkB = (lane & 3) ^ ((brow >> 1) & 3);
            gload16(Wg + (size_t)(n0 + brow) * KWp + k0 + gchunkB * 8,
                    &Bsl[wid * 1024 + j * 512]);
        }
        __syncthreads();
        short8 af[2], bf[4];
        #pragma unroll
        for (int mf = 0; mf < 2; ++mf) {
            int r = wr * 32 + mf * 16 + l15;
            af[mf] = *(const short8*)&Asl[r * 32 + (l4 ^ ((r >> 1) & 3)) * 8];
        }
        #pragma unroll
        for (int nf = 0; nf < 4; ++nf) {
            int r = wc * 64 + nf * 16 + l15;
            bf[nf] = *(const short8*)&Bsl[r * 32 + (l4 ^ ((r >> 1) & 3)) * 8];
        }
        #pragma unroll
        for (int mf = 0; mf < 2; ++mf)
            #pragma unroll
            for (int nf = 0; nf < 4; ++nf)
                acc[mf][nf] = __builtin_amdgcn_mfma_f32_16x16x32_bf16(
                                  af[mf], bf[nf], acc[mf][nf], 0, 0, 0);
    }
    #pragma unroll
    for (int mf = 0; mf < 2; ++mf)
        #pragma unroll
        for (int nf = 0; nf < 4; ++nf)
            #pragma unroll
            for (int reg = 0; reg < 4; ++reg) {
                int b = m0 + wr * 32 + mf * 16 + l4 * 4 + reg;
                int n = n0 + wc * 64 + nf * 16 + l15;
                gates[(size_t)b * 2048 + n] = acc[mf][nf][reg];
            }
}

// ---------------------------------------------------------------------------
// k_lstm: elementwise LSTM epilogue over [B,H].
// ---------------------------------------------------------------------------
__global__ __launch_bounds__(256) void k_lstm(
        const float* __restrict__ gates, const float* __restrict__ Wb,
        const float* __restrict__ cs, float* __restrict__ out) {
    const int idx = blockIdx.x * 256 + threadIdx.x;
    const int b = idx >> 9, h = idx & 511;
    const float* g = gates + (size_t)b * 2048;
    float f  = sigmoidf_(g[h]        + Wb[h]);
    float o  = sigmoidf_(g[512 + h]  + Wb[512 + h]);
    float ii = sigmoidf_(g[1024 + h] + Wb[1024 + h]);
    float ch = tanhf(    g[1536 + h] + Wb[1536 + h]);
    float c  = f * cs[idx] + ii * ch;
    out[idx] = o * tanhf(c);
}

extern "C" void kernel_launch(void* const* d_in, const int* in_sizes, int n_in,
                              void* d_out, int out_size, void* d_ws, size_t ws_size,
                              hipStream_t stream) {
    const float* x      = (const float*)d_in[0];
    const float* h_enc  = (const float*)d_in[1];
    const float* phi    = (const float*)d_in[2];
    const float* cell   = (const float*)d_in[3];
    const float* h_summ = (const float*)d_in[4];
    // d_in[5] c_summ: unused by the reference
    const float* W_w    = (const float*)d_in[6];
    const float* W_b    = (const float*)d_in[7];
    const float* v_w    = (const float*)d_in[8];
    // d_in[9] v_b: softmax-invariant, dropped
    const float* lq_w   = (const float*)d_in[10];
    const float* lq_b   = (const float*)d_in[11];
    const float* lk_w   = (const float*)d_in[12];
    const float* lk_b   = (const float*)d_in[13];
    const float* ls_w   = (const float*)d_in[14];
    const float* ls_b   = (const float*)d_in[15];
    float* out = (float*)d_out;

    char* w = (char*)d_ws;
    float* qs     = (float*)(w);                            // 4.00 MB
    float* scores = (float*)(w + 4194304);                  // 0.40 MB
    float* cs     = (float*)(w + 4603904);                  // 4.00 MB
    float* gates  = (float*)(w + 8798208);                  // 16.78 MB
    u16*   Aq     = (u16*)  (w + 25575424);                 // 4.19 MB
    u16*   Wq     = (u16*)  (w + 29769728);                 // 1.05 MB
    u16*   Wg     = (u16*)  (w + 30818304);                 // 3.41 MB
    u16*   Xb     = (u16*)  (w + 34226176);                 // 3.41 MB  (end ~35.9 MB)

    hipMemsetAsync(scores, 0, (size_t)Bm * Tm * sizeof(float), stream);
    k_pack<<<dim3(2048, 4), 256, 0, stream>>>(h_enc, h_summ, lq_w, ls_w, W_w, x, Aq, Wq, Wg, Xb);
    k_qs_mfma<<<dim3(Bm / 64, Hm / 64), 256, 0, stream>>>(Aq, Wq, lq_b, ls_b, lk_b, qs);
    k_scores_mfma<<<dim3(Hm / 128, (Tm * Bm) / 128), 256, 0, stream>>>(phi, lk_w, qs, v_w, scores);
    k_attn<<<dim3(Bm), 256, 0, stream>>>(phi, cell, scores, Xb, cs);
    k_gates_mfma<<<dim3(Bm / 64, 2048 / 128), 256, 0, stream>>>(Xb, Wg, gates);
    k_lstm<<<dim3((Bm * Hm) / 256), 256, 0, stream>>>(gates, W_b, cs, out);
}

// Round 4
// 340.808 us; speedup vs baseline: 3.4650x; 1.1194x over previous
//
#include <hip/hip_runtime.h>
#include <math.h>

#define Bm 2048
#define Hm 512
#define Em 300
#define Tm 50
#define KWm 812   // H + E
#define KWp 832   // padded to multiple of 32

typedef unsigned short u16;
typedef unsigned int u32;
typedef __attribute__((ext_vector_type(8))) short short8;
typedef __attribute__((ext_vector_type(8))) u16 ushort8v;
typedef __attribute__((ext_vector_type(4))) float f32x4;

__device__ __forceinline__ float sigmoidf_(float x) { return 1.f / (1.f + __expf(-x)); }

// fp32 -> bf16 bits, round-to-nearest-even
__device__ __forceinline__ u16 bfr(float x) {
    union { float f; u32 u; } c; c.f = x;
    u32 u = c.u;
    u += 0x7FFFu + ((u >> 16) & 1u);
    return (u16)(u >> 16);
}
__device__ __forceinline__ ushort8v cvt8(const float* __restrict__ p) {
    f32x4 v0 = *(const f32x4*)p;
    f32x4 v1 = *(const f32x4*)(p + 4);
    ushort8v r;
    r[0] = bfr(v0[0]); r[1] = bfr(v0[1]); r[2] = bfr(v0[2]); r[3] = bfr(v0[3]);
    r[4] = bfr(v1[0]); r[5] = bfr(v1[1]); r[6] = bfr(v1[2]); r[7] = bfr(v1[3]);
    return r;
}

// async global(bf16,16B) -> LDS, linear dest (wave-uniform base + lane*16)
__device__ __forceinline__ void gload16(const u16* g, u16* l) {
    __builtin_amdgcn_global_load_lds((const __attribute__((address_space(1))) void*)g,
                                     (__attribute__((address_space(3))) void*)l, 16, 0, 0);
}

// ---------------------------------------------------------------------------
// k_pack_phi: phi fp32 [T*B*512] -> bf16, grid-stride, 8 elems/thread/iter.
// ---------------------------------------------------------------------------
__global__ __launch_bounds__(256) void k_pack_phi(
        const float* __restrict__ phi, u16* __restrict__ phib) {
    const size_t nvec = (size_t)Tm * Bm * 512 / 8;
    for (size_t i = (size_t)blockIdx.x * 256 + threadIdx.x; i < nvec;
         i += (size_t)gridDim.x * 256)
        *(ushort8v*)&phib[i * 8] = cvt8(phi + i * 8);
}

// ---------------------------------------------------------------------------
// k_pack: small bf16 conversions/concats.
// job 0: Aq[2048][1024] = bf16([h_enc | h_summ])
// job 1: Wq[512][1024]  = bf16([lq_w | ls_w])
// job 2: Wg[2048][832]  = bf16(W_w) zero-padded
// job 3: Xb[2048][512..831] = bf16(x) zero-padded
// job 4: lkwb[512][512] = bf16(lk_w)
// ---------------------------------------------------------------------------
__global__ __launch_bounds__(256) void k_pack(
        const float* __restrict__ henc, const float* __restrict__ hsum,
        const float* __restrict__ lq, const float* __restrict__ ls,
        const float* __restrict__ Ww, const float* __restrict__ x,
        const float* __restrict__ lkw,
        u16* __restrict__ Aq, u16* __restrict__ Wq,
        u16* __restrict__ Wg, u16* __restrict__ Xb, u16* __restrict__ lkwb) {
    const int job = blockIdx.y;
    const int r = blockIdx.x;
    const int tid = threadIdx.x;
    if (job == 0) {
        for (int c = tid; c < 1024; c += 256) {
            float v = (c < 512) ? henc[(size_t)r * 512 + c] : hsum[(size_t)r * 512 + (c - 512)];
            Aq[(size_t)r * 1024 + c] = bfr(v);
        }
    } else if (job == 1) {
        if (r < 512)
            for (int c = tid; c < 1024; c += 256) {
                float v = (c < 512) ? lq[(size_t)r * 512 + c] : ls[(size_t)r * 512 + (c - 512)];
                Wq[(size_t)r * 1024 + c] = bfr(v);
            }
    } else if (job == 2) {
        for (int c = tid; c < KWp; c += 256)
            Wg[(size_t)r * KWp + c] = (c < KWm) ? bfr(Ww[(size_t)r * KWm + c]) : (u16)0;
    } else if (job == 3) {
        for (int c = 512 + tid; c < KWp; c += 256)
            Xb[(size_t)r * KWp + c] = (c < KWm) ? bfr(x[(size_t)r * Em + (c - 512)]) : (u16)0;
    } else {
        if (r < 512)
            for (int c = tid; c < 512; c += 256)
                lkwb[(size_t)r * 512 + c] = bfr(lkw[(size_t)r * 512 + c]);
    }
}

// ---------------------------------------------------------------------------
// k_qs_mfma: qs[b,h] = [h_enc|h_summ]·[lq|ls]^T + (lq_b+ls_b+lk_b)[h]
// ---------------------------------------------------------------------------
__global__ __launch_bounds__(256) void k_qs_mfma(
        const u16* __restrict__ Aq, const u16* __restrict__ Wq,
        const float* __restrict__ lqb, const float* __restrict__ lsb,
        const float* __restrict__ lkb, float* __restrict__ qs) {
    __shared__ u16 Asl[64 * 32];
    __shared__ u16 Bsl[64 * 32];
    const int m0 = blockIdx.x * 64, n0 = blockIdx.y * 64;
    const int tid = threadIdx.x, lane = tid & 63, wid = tid >> 6;
    const int wr = wid >> 1, wc = wid & 1;
    const int l15 = lane & 15, l4 = lane >> 4;
    const int srow = (wid << 4) + (lane >> 2);
    const int gchunk = (lane & 3) ^ ((srow >> 1) & 3);
    f32x4 acc[2][2];
    #pragma unroll
    for (int i = 0; i < 2; ++i)
        #pragma unroll
        for (int j = 0; j < 2; ++j) acc[i][j] = (f32x4){0.f, 0.f, 0.f, 0.f};

    for (int k0 = 0; k0 < 1024; k0 += 32) {
        __syncthreads();
        gload16(Aq + (size_t)(m0 + srow) * 1024 + k0 + gchunk * 8, &Asl[wid * 512]);
        gload16(Wq + (size_t)(n0 + srow) * 1024 + k0 + gchunk * 8, &Bsl[wid * 512]);
        __syncthreads();
        short8 af[2], bf[2];
        #pragma unroll
        for (int mf = 0; mf < 2; ++mf) {
            int r = wr * 32 + mf * 16 + l15;
            af[mf] = *(const short8*)&Asl[r * 32 + (l4 ^ ((r >> 1) & 3)) * 8];
        }
        #pragma unroll
        for (int nf = 0; nf < 2; ++nf) {
            int r = wc * 32 + nf * 16 + l15;
            bf[nf] = *(const short8*)&Bsl[r * 32 + (l4 ^ ((r >> 1) & 3)) * 8];
        }
        #pragma unroll
        for (int mf = 0; mf < 2; ++mf)
            #pragma unroll
            for (int nf = 0; nf < 2; ++nf)
                acc[mf][nf] = __builtin_amdgcn_mfma_f32_16x16x32_bf16(
                                  af[mf], bf[nf], acc[mf][nf], 0, 0, 0);
    }
    #pragma unroll
    for (int mf = 0; mf < 2; ++mf)
        #pragma unroll
        for (int nf = 0; nf < 2; ++nf)
            #pragma unroll
            for (int reg = 0; reg < 4; ++reg) {
                int b = m0 + wr * 32 + mf * 16 + l4 * 4 + reg;
                int h = n0 + wc * 32 + nf * 16 + l15;
                qs[(size_t)b * Hm + h] = acc[mf][nf][reg] + lqb[h] + lsb[h] + lkb[h];
            }
}

// ---------------------------------------------------------------------------
// k_scores_mfma (dominant): E = phib(102400x512) @ lkwb^T, pure bf16 MFMA with
// global_load_lds staging (no in-loop conversion). Fused tanh/v_w/row-sum
// epilogue, atomicAdd into scores. 128x128 tile, 4 waves 2x2, 4x4 frags, BK=32.
// ---------------------------------------------------------------------------
__global__ __launch_bounds__(256) void k_scores_mfma(
        const u16* __restrict__ phib, const u16* __restrict__ lkwb,
        const float* __restrict__ qs2, const float* __restrict__ vw,
        float* __restrict__ scores) {
    __shared__ u16 Asl[128 * 32];
    __shared__ u16 Bsl[128 * 32];
    const int n0 = blockIdx.x * 128;
    const int m0 = blockIdx.y * 128;
    const int t  = m0 >> 11;
    const int b0 = m0 & (Bm - 1);
    const int tid = threadIdx.x, lane = tid & 63, wid = tid >> 6;
    const int wr = wid >> 1, wc = wid & 1;
    const int l15 = lane & 15, l4 = lane >> 4;
    const int srow_base = (wid << 5) + (lane >> 2);   // + j*16
    const int schunk = lane & 3;

    f32x4 acc[4][4];
    #pragma unroll
    for (int i = 0; i < 4; ++i)
        #pragma unroll
        for (int j = 0; j < 4; ++j) acc[i][j] = (f32x4){0.f, 0.f, 0.f, 0.f};

    for (int k0 = 0; k0 < 512; k0 += 32) {
        __syncthreads();
        #pragma unroll
        for (int j = 0; j < 2; ++j) {
            int r = srow_base + j * 16;
            int gc = schunk ^ ((r >> 1) & 3);
            gload16(phib + (size_t)(m0 + r) * 512 + k0 + gc * 8,
                    &Asl[((wid << 5) + j * 16) * 32]);
            gload16(lkwb + (size_t)(n0 + r) * 512 + k0 + gc * 8,
                    &Bsl[((wid << 5) + j * 16) * 32]);
        }
        __syncthreads();
        short8 af[4], bf[4];
        #pragma unroll
        for (int mf = 0; mf < 4; ++mf) {
            int r = wr * 64 + mf * 16 + l15;
            af[mf] = *(const short8*)&Asl[r * 32 + (l4 ^ ((r >> 1) & 3)) * 8];
        }
        #pragma unroll
        for (int nf = 0; nf < 4; ++nf) {
            int r = wc * 64 + nf * 16 + l15;
            bf[nf] = *(const short8*)&Bsl[r * 32 + (l4 ^ ((r >> 1) & 3)) * 8];
        }
        #pragma unroll
        for (int mf = 0; mf < 4; ++mf)
            #pragma unroll
            for (int nf = 0; nf < 4; ++nf)
                acc[mf][nf] = __builtin_amdgcn_mfma_f32_16x16x32_bf16(
                                  af[mf], bf[nf], acc[mf][nf], 0, 0, 0);
    }

    float vws[4];
    int av[4];
    #pragma unroll
    for (int nf = 0; nf < 4; ++nf) {
        av[nf] = n0 + wc * 64 + nf * 16 + l15;
        vws[nf] = vw[av[nf]];
    }
    #pragma unroll
    for (int mf = 0; mf < 4; ++mf) {
        #pragma unroll
        for (int reg = 0; reg < 4; ++reg) {
            int b = b0 + wr * 64 + mf * 16 + l4 * 4 + reg;
            const float* q = qs2 + (size_t)b * Hm;
            float s = 0.f;
            #pragma unroll
            for (int nf = 0; nf < 4; ++nf)
                s = fmaf(tanhf(acc[mf][nf][reg] + q[av[nf]]), vws[nf], s);
            #pragma unroll
            for (int o = 1; o < 16; o <<= 1) s += __shfl_xor(s, o);
            if (l15 == 0) atomicAdd(&scores[(size_t)b * Tm + t], s);
        }
    }
}

// ---------------------------------------------------------------------------
// k_attn: softmax over T, weighted sums over bf16 phi + fp32 cell.
// Thread t handles cols 2t, 2t+1. h_s -> bf16 Xb, c_s -> fp32.
// ---------------------------------------------------------------------------
__global__ __launch_bounds__(256) void k_attn(
        const u16* __restrict__ phib, const float* __restrict__ cell,
        const float* __restrict__ scores,
        u16* __restrict__ Xb, float* __restrict__ cs) {
    __shared__ float p[Tm];
    const int b = blockIdx.x;
    const int tid = threadIdx.x;
    if (tid < 64) {
        float s = (tid < Tm) ? scores[(size_t)b * Tm + tid] : -INFINITY;
        float m = s;
        #pragma unroll
        for (int o = 32; o; o >>= 1) m = fmaxf(m, __shfl_xor(m, o));
        float ex = (tid < Tm) ? __expf(s - m) : 0.f;
        float sum = ex;
        #pragma unroll
        for (int o = 32; o; o >>= 1) sum += __shfl_xor(sum, o);
        if (tid < Tm) p[tid] = ex / sum;
    }
    __syncthreads();
    const int c0 = tid * 2;
    float ah0 = 0.f, ah1 = 0.f, ac0 = 0.f, ac1 = 0.f;
    for (int t = 0; t < Tm; ++t) {
        float w = p[t];
        const size_t rb = ((size_t)t * Bm + b) * 512 + c0;
        u32 ph2 = *(const u32*)&phib[rb];
        float2 ce2 = *(const float2*)&cell[rb];
        float p0 = __uint_as_float(ph2 << 16);
        float p1 = __uint_as_float(ph2 & 0xFFFF0000u);
        ah0 = fmaf(w, p0, ah0);
        ah1 = fmaf(w, p1, ah1);
        ac0 = fmaf(w, ce2.x, ac0);
        ac1 = fmaf(w, ce2.y, ac1);
    }
    *(u32*)&Xb[(size_t)b * KWp + c0] = (u32)bfr(ah0) | ((u32)bfr(ah1) << 16);
    *(float2*)&cs[(size_t)b * Hm + c0] = make_float2(ac0, ac1);
}

// ---------------------------------------------------------------------------
// k_gates_mfma: gates[2048][2048] = Xb(2048x832) @ Wg^T(2048x832), bf16 MFMA.
// ---------------------------------------------------------------------------
__global__ __launch_bounds__(256) void k_gates_mfma(
        const u16* __restrict__ Xb, const u16* __restrict__ Wg,
        float* __restrict__ gates) {
    __shared__ u16 Asl[64 * 32];
    __shared__ u16 Bsl[128 * 32];
    const int m0 = blockIdx.x * 64, n0 = blockIdx.y * 128;
    const int tid = threadIdx.x, lane = tid & 63, wid = tid >> 6;
    const int wr = wid >> 1, wc = wid & 1;
    const int l15 = lane & 15, l4 = lane >> 4;
    const int srow = (wid << 4) + (lane >> 2);
    const int gchunkA = (lane & 3) ^ ((srow >> 1) & 3);
    f32x4 acc[2][4];
    #pragma unroll
    for (int i = 0; i < 2; ++i)
        #pragma unroll
        for (int j = 0; j < 4; ++j) acc[i][j] = (f32x4){0.f, 0.f, 0.f, 0.f};

    for (int k0 = 0; k0 < KWp; k0 += 32) {
        __syncthreads();
        gload16(Xb + (size_t)(m0 + srow) * KWp + k0 + gchunkA * 8, &Asl[wid * 512]);
        #pragma unroll
        for (int j = 0; j < 2; ++j) {
            int brow = (wid << 5) + (j << 4) + (lane >> 2);
            int gchunkB = (lane & 3) ^ ((brow >> 1) & 3);
            gload16(Wg + (size_t)(n0 + brow) * KWp + k0 + gchunkB * 8,
                    &Bsl[wid * 1024 + j * 512]);
        }
        __syncthreads();
        short8 af[2], bf[4];
        #pragma unroll
        for (int mf = 0; mf < 2; ++mf) {
            int r = wr * 32 + mf * 16 + l15;
            af[mf] = *(const short8*)&Asl[r * 32 + (l4 ^ ((r >> 1) & 3)) * 8];
        }
        #pragma unroll
        for (int nf = 0; nf < 4; ++nf) {
            int r = wc * 64 + nf * 16 + l15;
            bf[nf] = *(const short8*)&Bsl[r * 32 + (l4 ^ ((r >> 1) & 3)) * 8];
        }
        #pragma unroll
        for (int mf = 0; mf < 2; ++mf)
            #pragma unroll
            for (int nf = 0; nf < 4; ++nf)
                acc[mf][nf] = __builtin_amdgcn_mfma_f32_16x16x32_bf16(
                                  af[mf], bf[nf], acc[mf][nf], 0, 0, 0);
    }
    #pragma unroll
    for (int mf = 0; mf < 2; ++mf)
        #pragma unroll
        for (int nf = 0; nf < 4; ++nf)
            #pragma unroll
            for (int reg = 0; reg < 4; ++reg) {
                int b = m0 + wr * 32 + mf * 16 + l4 * 4 + reg;
                int n = n0 + wc * 64 + nf * 16 + l15;
                gates[(size_t)b * 2048 + n] = acc[mf][nf][reg];
            }
}

// ---------------------------------------------------------------------------
// k_lstm: elementwise LSTM epilogue over [B,H].
// ---------------------------------------------------------------------------
__global__ __launch_bounds__(256) void k_lstm(
        const float* __restrict__ gates, const float* __restrict__ Wb,
        const float* __restrict__ cs, float* __restrict__ out) {
    const int idx = blockIdx.x * 256 + threadIdx.x;
    const int b = idx >> 9, h = idx & 511;
    const float* g = gates + (size_t)b * 2048;
    float f  = sigmoidf_(g[h]        + Wb[h]);
    float o  = sigmoidf_(g[512 + h]  + Wb[512 + h]);
    float ii = sigmoidf_(g[1024 + h] + Wb[1024 + h]);
    float ch = tanhf(    g[1536 + h] + Wb[1536 + h]);
    float c  = f * cs[idx] + ii * ch;
    out[idx] = o * tanhf(c);
}

extern "C" void kernel_launch(void* const* d_in, const int* in_sizes, int n_in,
                              void* d_out, int out_size, void* d_ws, size_t ws_size,
                              hipStream_t stream) {
    const float* x      = (const float*)d_in[0];
    const float* h_enc  = (const float*)d_in[1];
    const float* phi    = (const float*)d_in[2];
    const float* cell   = (const float*)d_in[3];
    const float* h_summ = (const float*)d_in[4];
    // d_in[5] c_summ: unused by the reference
    const float* W_w    = (const float*)d_in[6];
    const float* W_b    = (const float*)d_in[7];
    const float* v_w    = (const float*)d_in[8];
    // d_in[9] v_b: softmax-invariant, dropped
    const float* lq_w   = (const float*)d_in[10];
    const float* lq_b   = (const float*)d_in[11];
    const float* lk_w   = (const float*)d_in[12];
    const float* lk_b   = (const float*)d_in[13];
    const float* ls_w   = (const float*)d_in[14];
    const float* ls_b   = (const float*)d_in[15];
    float* out = (float*)d_out;

    char* w = (char*)d_ws;
    // phib: 0 .. 104,857,600 (52.4M bf16). gates (16.78 MB) ALIASES phib:
    // phib's last reader (k_attn) finishes before k_gates_mfma writes gates.
    u16*   phib   = (u16*)  (w);
    float* gates  = (float*)(w);
    float* qs     = (float*)(w + 104857600);                // 4.00 MB
    float* scores = (float*)(w + 109051904);                // 0.40 MB
    float* cs     = (float*)(w + 109461504);                // 4.00 MB
    u16*   Aq     = (u16*)  (w + 113655808);                // 4.19 MB
    u16*   Wq     = (u16*)  (w + 117850112);                // 1.05 MB
    u16*   Wg     = (u16*)  (w + 118898688);                // 3.41 MB
    u16*   Xb     = (u16*)  (w + 122306560);                // 3.41 MB
    u16*   lkwb   = (u16*)  (w + 125714432);                // 0.52 MB (end ~126.2 MB)

    hipMemsetAsync(scores, 0, (size_t)Bm * Tm * sizeof(float), stream);
    k_pack<<<dim3(2048, 5), 256, 0, stream>>>(h_enc, h_summ, lq_w, ls_w, W_w, x, lk_w,
                                              Aq, Wq, Wg, Xb, lkwb);
    k_pack_phi<<<dim3(2048), 256, 0, stream>>>(phi, phib);
    k_qs_mfma<<<dim3(Bm / 64, Hm / 64), 256, 0, stream>>>(Aq, Wq, lq_b, ls_b, lk_b, qs);
    k_scores_mfma<<<dim3(Hm / 128, (Tm * Bm) / 128), 256, 0, stream>>>(phib, lkwb, qs, v_w, scores);
    k_attn<<<dim3(Bm), 256, 0, stream>>>(phib, cell, scores, Xb, cs);
    k_gates_mfma<<<dim3(Bm / 64, 2048 / 128), 256, 0, stream>>>(Xb, Wg, gates);
    k_lstm<<<dim3((Bm * Hm) / 256), 256, 0, stream>>>(gates, W_b, cs, out);
}